// Round 2
// baseline (579.762 us; speedup 1.0000x reference)
//
#include <hip/hip_runtime.h>
#include <stdint.h>

// GEMM: C[M,N] = X[M,K] * W[N,K]^T + bias, group-dequantized W (group=64 along K).
// R6: (a) GEMM inner loop switched to v_mfma_f32_32x32x16_bf16 (2495 TF ubench
// ceiling vs 2176 for 16x16x32) with 2 long phases per K-tile (16 MFMA each,
// 4 barriers/tile instead of 8) and deeper counted-vmcnt: all 8 staging loads
// front-loaded in phase 1, WAIT vmcnt(8) end-ph1 / vmcnt(4) end-ph2 so every
// retire is >=2 long phases after issue. Swizzle invariant: XOR term
// (row>>1)&3 == (l31>>1)&3 for all fragments (subtile offsets are multiples
// of 32) -> conflict-free reads preserved (R5 measured 0 conflicts).
// (b) cvt rewritten as canonical grid-stride (2064 blocks, ~12 units/thread)
// -- roofline-by-construction diagnostic for the stable ~245us non-gemm
// residue: total-minus-gemm delta tells us cvt-slow vs harness-overhead.

typedef __attribute__((ext_vector_type(8))) short short8;       // 8 bf16 = 4 VGPRs
typedef __attribute__((ext_vector_type(8))) unsigned short ushort8;
typedef __attribute__((ext_vector_type(4))) float f32x4;
typedef __attribute__((ext_vector_type(16))) float f32x16;
typedef __attribute__((ext_vector_type(4))) float float4v;
typedef __attribute__((ext_vector_type(4))) int int4v;

typedef __attribute__((address_space(1))) void g_void;
typedef __attribute__((address_space(3))) void l_void;

__device__ __forceinline__ unsigned short f2bf(float f) {
  union { float f; unsigned int u; } v; v.f = f;
  unsigned int r = v.u + 0x7FFFu + ((v.u >> 16) & 1u);  // round-to-nearest-even
  return (unsigned short)(r >> 16);
}

__device__ __forceinline__ void async_copy16(const void* g, void* l) {
  __builtin_amdgcn_global_load_lds((const g_void*)g, (l_void*)l, 16, 0, 0);
}

// barrier that the compiler cannot move LDS ops across, WITHOUT the
// vmcnt(0)+lgkmcnt(0) drain __syncthreads() forces.
__device__ __forceinline__ void wg_barrier() {
  asm volatile("" ::: "memory");
  __builtin_amdgcn_s_barrier();
  asm volatile("" ::: "memory");
}

#define WAIT_VMCNT(N) asm volatile("s_waitcnt vmcnt(" #N ")" ::: "memory")

// ---- conversion: X fp32->bf16 and W int32*scale->bf16, grid-stride --------
__global__ __launch_bounds__(256) void cvt_kernel(
    const float* __restrict__ x, const int* __restrict__ w,
    const float* __restrict__ s, unsigned short* __restrict__ ox,
    unsigned short* __restrict__ ow, int n8x, int n8w, int gx) {
  if ((int)blockIdx.x < gx) {
    const int stride = gx * 256;
    for (int t = blockIdx.x * 256 + threadIdx.x; t < n8x; t += stride) {
      const float4v* xp = (const float4v*)x + (size_t)t * 2;
      float4v a = xp[0], b = xp[1];
      ushort8 r;
      r[0] = f2bf(a[0]); r[1] = f2bf(a[1]); r[2] = f2bf(a[2]); r[3] = f2bf(a[3]);
      r[4] = f2bf(b[0]); r[5] = f2bf(b[1]); r[6] = f2bf(b[2]); r[7] = f2bf(b[3]);
      *(ushort8*)(ox + (size_t)t * 8) = r;
    }
  } else {
    const int stride = ((int)gridDim.x - gx) * 256;
    for (int t = ((int)blockIdx.x - gx) * 256 + threadIdx.x; t < n8w; t += stride) {
      const int4v* wp = (const int4v*)w + (size_t)t * 2;
      int4v q0 = wp[0], q1 = wp[1];
      float sc = s[t >> 3];  // GROUP_SIZE=64 = 8 threads x 8 elems
      ushort8 r;
      r[0] = f2bf((float)q0[0] * sc); r[1] = f2bf((float)q0[1] * sc);
      r[2] = f2bf((float)q0[2] * sc); r[3] = f2bf((float)q0[3] * sc);
      r[4] = f2bf((float)q1[0] * sc); r[5] = f2bf((float)q1[1] * sc);
      r[6] = f2bf((float)q1[2] * sc); r[7] = f2bf((float)q1[3] * sc);
      *(ushort8*)(ow + (size_t)t * 8) = r;
    }
  }
}

// ---- main GEMM: 256x256 tile, BK=64, 8 waves, 32x32x16 MFMA, 2-phase ------
// LDS (128 KiB): A bufs [2][2kh][256 rows][32 k] at 0..64K, B same at 64K..128K.
// Unit = one (buf,op,kh) 16 KiB slab (rows of 64 B = 4 chunks of 16 B).
// Chunk swizzle: physical chunk pc of row r holds logical chunk pc^((r>>1)&3)
// (applied to the per-lane GLOBAL source on the write side, since
// global_load_lds dests are linear; and to the ds_read address on read side).

#define MF32(a, b, c) __builtin_amdgcn_mfma_f32_32x32x16_bf16(a, b, c, 0, 0, 0)

// 12 ds_read_b128: A frags (4 m-subtiles x 2 k-steps), B frags (2 n x 2 k)
#define READ12(AU, BU) do {                              \
    const unsigned char* _a = (AU) + abase;              \
    const unsigned char* _b = (BU) + bbase;              \
    a00 = *(const short8*)(_a + ca0);                    \
    a10 = *(const short8*)(_a + 2048 + ca0);             \
    a20 = *(const short8*)(_a + 4096 + ca0);             \
    a30 = *(const short8*)(_a + 6144 + ca0);             \
    a01 = *(const short8*)(_a + ca1);                    \
    a11 = *(const short8*)(_a + 2048 + ca1);             \
    a21 = *(const short8*)(_a + 4096 + ca1);             \
    a31 = *(const short8*)(_a + 6144 + ca1);             \
    b00 = *(const short8*)(_b + ca0);                    \
    b10 = *(const short8*)(_b + 2048 + ca0);             \
    b01 = *(const short8*)(_b + ca1);                    \
    b11 = *(const short8*)(_b + 2048 + ca1);             \
  } while (0)

// 16 MFMA: ks0 for all 8 (m,n) tiles, then ks1 (dep distance 8 per acc)
#define MFMA16() do {                                    \
    acc[0][0] = MF32(a00, b00, acc[0][0]);               \
    acc[1][0] = MF32(a10, b00, acc[1][0]);               \
    acc[2][0] = MF32(a20, b00, acc[2][0]);               \
    acc[3][0] = MF32(a30, b00, acc[3][0]);               \
    acc[0][1] = MF32(a00, b10, acc[0][1]);               \
    acc[1][1] = MF32(a10, b10, acc[1][1]);               \
    acc[2][1] = MF32(a20, b10, acc[2][1]);               \
    acc[3][1] = MF32(a30, b10, acc[3][1]);               \
    acc[0][0] = MF32(a01, b01, acc[0][0]);               \
    acc[1][0] = MF32(a11, b01, acc[1][0]);               \
    acc[2][0] = MF32(a21, b01, acc[2][0]);               \
    acc[3][0] = MF32(a31, b01, acc[3][0]);               \
    acc[0][1] = MF32(a01, b11, acc[0][1]);               \
    acc[1][1] = MF32(a11, b11, acc[1][1]);               \
    acc[2][1] = MF32(a21, b11, acc[2][1]);               \
    acc[3][1] = MF32(a31, b11, acc[3][1]);               \
  } while (0)

#define PRIO1 __builtin_amdgcn_s_setprio(1)
#define PRIO0 __builtin_amdgcn_s_setprio(0)

__device__ __forceinline__ void stage2(const unsigned short* src, int rstride,
                                       unsigned char* dst) {
  async_copy16(src, dst);                    // rows [0,128)
  async_copy16(src + rstride, dst + 8192);   // rows [128,256)
}

__global__ __launch_bounds__(512, 2) void gemm_8p(
    const unsigned short* __restrict__ Xb,  // bf16 [M][K]
    const unsigned short* __restrict__ Wb,  // bf16 [N][K]
    const float* __restrict__ bias,
    float* __restrict__ C, int M, int N, int K) {
  __shared__ __align__(16) unsigned char smem[131072];
  const int tid = threadIdx.x;
  const int lane = tid & 63, w = tid >> 6;
  const int wm = w >> 2, wn = w & 3;   // 2M x 4N waves, per-wave 128x64
  const int l31 = lane & 31, kg = lane >> 5;

  // T1: XCD-aware bijective swizzle (grid % 8 == 0 guaranteed by host gate)
  const int nbn = N >> 8;
  int bid = blockIdx.x;
  {
    const int nwg = gridDim.x;
    if ((nwg & 7) == 0) bid = (bid & 7) * (nwg >> 3) + (bid >> 3);
  }
  const int m0 = (bid / nbn) << 8;
  const int n0 = (bid % nbn) << 8;

  // fragment read addressing: row = (m-sub + l31), chunk c_log = ks*2 + kg,
  // phys = c_log ^ ((row>>1)&3) == c_log ^ ((l31>>1)&3)  (subtiles % 32 == 0)
  const int xr = (l31 >> 1) & 3;
  const int ca0 = ((0 + kg) ^ xr) << 4;   // ks=0
  const int ca1 = ((2 + kg) ^ xr) << 4;   // ks=1
  const int abase = (wm * 128 + l31) * 64;
  const int bbase = (wn * 64 + l31) * 64;

  // staging: thread -> (row = tid>>2 [+128 for 2nd load], logical chunk lc)
  const int rl = tid >> 2;
  const int lc = (tid & 3) ^ ((tid >> 3) & 3);  // inverse swizzle on source
  const unsigned short* pA = Xb + (size_t)(m0 + rl) * K + lc * 8;
  const unsigned short* pB = Wb + (size_t)(n0 + rl) * K + lc * 8;
  const int rstride = K << 7;   // 128 rows in elements
  const int wuo = w << 10;      // wave-uniform LDS dest offset (lane*16 by HW)

  f32x16 acc[4][2];
#pragma unroll
  for (int i = 0; i < 4; i++)
#pragma unroll
    for (int j = 0; j < 2; j++) acc[i][j] = (f32x16)(0.f);

  const int NT = K >> 6;

  // prologue: stage tile 0 -> buf 0, order A-kh0,B-kh0,A-kh1,B-kh1 (8 loads)
  stage2(pA, rstride, smem + wuo);
  stage2(pB, rstride, smem + 65536 + wuo);
  stage2(pA + 32, rstride, smem + 16384 + wuo);
  stage2(pB + 32, rstride, smem + 65536 + 16384 + wuo);
  WAIT_VMCNT(4);   // retire kh0 units; kh1 (4 loads) stays in flight
  wg_barrier();

  short8 a00, a10, a20, a30, a01, a11, a21, a31, b00, b10, b01, b11;

  // invariant entering tile t: 4 outstanding loads = tile t's kh1 units
  for (int t = 0; t < NT - 1; ++t) {
    const int p = t & 1;
    const unsigned char* Au = smem + p * 32768;
    const unsigned char* Bu = smem + 65536 + p * 32768;
    unsigned char* Aq = smem + (p ^ 1) * 32768 + wuo;
    unsigned char* Bq = smem + 65536 + (p ^ 1) * 32768 + wuo;
    const unsigned short* sA = pA + (size_t)(t + 1) * 64;
    const unsigned short* sB = pB + (size_t)(t + 1) * 64;

    // phase 1: kh0 compute | stage ALL of tile t+1 (8 loads, front-loaded)
    READ12(Au, Bu);
    stage2(sA, rstride, Aq);
    stage2(sB, rstride, Bq);
    stage2(sA + 32, rstride, Aq + 16384);
    stage2(sB + 32, rstride, Bq + 16384);
    wg_barrier();
    PRIO1; MFMA16(); PRIO0;
    WAIT_VMCNT(8);   // retire tile t's kh1 (issued 2 long phases ago)
    wg_barrier();
    // phase 2: kh1 compute | no staging
    READ12(Au + 16384, Bu + 16384);
    wg_barrier();
    PRIO1; MFMA16(); PRIO0;
    WAIT_VMCNT(4);   // retire tile t+1's kh0; its kh1 stays in flight
    wg_barrier();
  }

  // final tile (no staging): entering with its kh1 units still in flight
  {
    const int p = (NT - 1) & 1;
    const unsigned char* Au = smem + p * 32768;
    const unsigned char* Bu = smem + 65536 + p * 32768;
    READ12(Au, Bu);
    wg_barrier();
    PRIO1; MFMA16(); PRIO0;
    WAIT_VMCNT(0);   // drain kh1 units (only non-counted wait in the kernel)
    wg_barrier();
    READ12(Au + 16384, Bu + 16384);
    wg_barrier();
    PRIO1; MFMA16(); PRIO0;
  }

  // epilogue: 32x32 C layout: col = lane&31, row = (r&3) + 8*(r>>2) + 4*kg
  const int gm = m0 + wm * 128 + 4 * kg;
  const int gn = n0 + wn * 64 + l31;
  const float bv0 = bias[gn], bv1 = bias[gn + 32];
#pragma unroll
  for (int mt = 0; mt < 4; ++mt) {
#pragma unroll
    for (int nt = 0; nt < 2; ++nt) {
      const float bv = nt ? bv1 : bv0;
      const int col = gn + nt * 32;
      f32x16 v = acc[mt][nt];
#pragma unroll
      for (int r = 0; r < 16; ++r) {
        const int row = gm + mt * 32 + (r & 3) + 8 * (r >> 2);
        C[(size_t)row * N + col] = v[r] + bv;
      }
    }
  }
}

// ---- fallback: fused dequant GEMM (odd shapes / tiny ws; never bounded) --
#define BM 128
#define BN 128
#define BK 64

__global__ __launch_bounds__(256) void gemm_fused(
    const float* __restrict__ Xf, const int* __restrict__ Wq,
    const float* __restrict__ Ws, const float* __restrict__ bias,
    float* __restrict__ C, int M, int N, int K) {
  __shared__ unsigned char smem[(BM * BK + BN * BK) * 2];
  const int tid = threadIdx.x;
  const int lane = tid & 63, wid = tid >> 6;
  const int m0 = blockIdx.y * BM, n0 = blockIdx.x * BN;
  const int sr = lane >> 3, fc = (lane & 7) ^ sr;
  const int arow = m0 + wid * 32 + sr, brow = n0 + wid * 32 + sr;
  unsigned char* As = smem;
  unsigned char* Bs = smem + BM * BK * 2;
  unsigned char* stA = As + wid * 4096 + lane * 16;
  unsigned char* stB = Bs + wid * 4096 + lane * 16;
  const int l31 = lane & 31, lh = lane >> 5, le = lane & 7;
  const int wm = (wid & 1) * 64, wn = (wid >> 1) * 64;
  const unsigned char* Aw = As + (wm + l31) * 128;
  const unsigned char* Bw = Bs + (wn + l31) * 128;
  const int Kg = K >> 6;

  f32x16 acc[2][2];
#pragma unroll
  for (int i = 0; i < 2; i++)
#pragma unroll
    for (int j = 0; j < 2; j++) acc[i][j] = (f32x16)(0.f);

  for (int k0 = 0; k0 < K; k0 += BK) {
#pragma unroll
    for (int t = 0; t < 4; t++) {
      const float4v* xa = (const float4v*)(Xf + (size_t)(arow + t * 8) * K + k0 + fc * 8);
      float4v x0 = xa[0], x1 = xa[1];
      ushort8 ra;
      ra[0] = f2bf(x0[0]); ra[1] = f2bf(x0[1]); ra[2] = f2bf(x0[2]); ra[3] = f2bf(x0[3]);
      ra[4] = f2bf(x1[0]); ra[5] = f2bf(x1[1]); ra[6] = f2bf(x1[2]); ra[7] = f2bf(x1[3]);
      *(ushort8*)(stA + t * 1024) = ra;
      const int4v* wq = (const int4v*)(Wq + (size_t)(brow + t * 8) * K + k0 + fc * 8);
      int4v q0 = wq[0], q1 = wq[1];
      float sc = Ws[(size_t)(brow + t * 8) * Kg + (k0 >> 6)];
      ushort8 rb;
      rb[0] = f2bf((float)q0[0] * sc); rb[1] = f2bf((float)q0[1] * sc);
      rb[2] = f2bf((float)q0[2] * sc); rb[3] = f2bf((float)q0[3] * sc);
      rb[4] = f2bf((float)q1[0] * sc); rb[5] = f2bf((float)q1[1] * sc);
      rb[6] = f2bf((float)q1[2] * sc); rb[7] = f2bf((float)q1[3] * sc);
      *(ushort8*)(stB + t * 1024) = rb;
    }
    __syncthreads();
#pragma unroll
    for (int s = 0; s < 4; s++) {
      const int off = ((s + 4 * lh) ^ le) << 4;
      short8 a0 = *(const short8*)(Aw + off);
      short8 a1 = *(const short8*)(Aw + 4096 + off);
      short8 b0 = *(const short8*)(Bw + off);
      short8 b1 = *(const short8*)(Bw + 4096 + off);
      acc[0][0] = __builtin_amdgcn_mfma_f32_32x32x16_bf16(a0, b0, acc[0][0], 0, 0, 0);
      acc[0][1] = __builtin_amdgcn_mfma_f32_32x32x16_bf16(a0, b1, acc[0][1], 0, 0, 0);
      acc[1][0] = __builtin_amdgcn_mfma_f32_32x32x16_bf16(a1, b0, acc[1][0], 0, 0, 0);
      acc[1][1] = __builtin_amdgcn_mfma_f32_32x32x16_bf16(a1, b1, acc[1][1], 0, 0, 0);
    }
    __syncthreads();
  }

  const int gm = m0 + wm + 4 * lh, gn = n0 + wn + l31;
#pragma unroll
  for (int j = 0; j < 2; j++) {
    const int col = gn + j * 32;
    const float bv = bias[col];
#pragma unroll
    for (int i = 0; i < 2; i++) {
      const int rbase = gm + i * 32;
      f32x16 v = acc[i][j];
#pragma unroll
      for (int r = 0; r < 16; r++) {
        const int row = rbase + (r & 3) + 8 * (r >> 2);
        C[(size_t)row * N + col] = v[r] + bv;
      }
    }
  }
}

extern "C" void kernel_launch(void* const* d_in, const int* in_sizes, int n_in,
                              void* d_out, int out_size, void* d_ws, size_t ws_size,
                              hipStream_t stream) {
  const float* x = (const float*)d_in[0];
  const int* wq = (const int*)d_in[1];
  const float* wsc = (const float*)d_in[2];
  const float* bias = (const float*)d_in[3];
  float* out = (float*)d_out;

  const int N = in_sizes[3];            // D_out (bias length)
  const int K = in_sizes[1] / N;        // D_in
  const int M = in_sizes[0] / K;        // B*S

  const size_t needX = (size_t)M * K * 2;
  const size_t needW = (size_t)N * K * 2;
  const bool big = (M % 256 == 0) && (N % 256 == 0) && (K % 64 == 0) && (K >= 128);

  if (big && ws_size >= needX + needW) {
    unsigned short* Xb = (unsigned short*)d_ws;
    unsigned short* Wb = (unsigned short*)((char*)d_ws + needX);
    const int n8x = (M * K) / 8, n8w = (N * K) / 8;
    // grid-stride cvt: ~8 blocks/CU, X:W work ratio = 2:1
    const int gx = 1376, gw = 688;
    cvt_kernel<<<gx + gw, 256, 0, stream>>>(x, wq, wsc, Xb, Wb, n8x, n8w, gx);
    dim3 grid((M / 256) * (N / 256));
    gemm_8p<<<grid, 512, 0, stream>>>(Xb, Wb, bias, out, M, N, K);
  } else {
    dim3 grid(N / BN, M / BM), block(256);
    gemm_fused<<<grid, block, 0, stream>>>(x, wq, wsc, bias, out, M, N, K);
  }
}

// Round 3
// 571.746 us; speedup vs baseline: 1.0140x; 1.0140x over previous
//
#include <hip/hip_runtime.h>
#include <stdint.h>

// GEMM: C[M,N] = X[M,K] * W[N,K]^T + bias, group-dequantized W (group=64 along K).
// R7: fix the 32x32x16 bank-conflict regression (R6: exactly 4 conflict-cyc
// per ds_read_b128, same signature as R0's 32x32 kernel). Mechanism theory:
// LDS b128 wave-reads are conflict-free only when the 64 lanes form a
// permutation of a contiguous 1KiB block (R5's 16-row x 4-chunk pattern);
// 32-row sparse coverage costs +4cyc/read. Fix: unit layout [ks][256r][32B]
// (32B rows, 2 chunks) with phys chunk pc = kg ^ ((row>>2)&1) -> the 32x32
// fragment read (rows=l31, kg=lane>>5) covers a full contiguous 1KiB once;
// 8-lane groups hit all 32 banks exactly once. Writes stay linear for
// global_load_lds; inverse swizzle folded into per-lane global source.
// Also: ONE barrier per phase (2/tile; regions disjoint by kh-alternation +
// double-buffer at skew<=1), staging distributed kh0@ph1 / kh1@ph2, each
// counted vmcnt(4) retire one full phase after issue.

typedef __attribute__((ext_vector_type(8))) short short8;       // 8 bf16 = 4 VGPRs
typedef __attribute__((ext_vector_type(8))) unsigned short ushort8;
typedef __attribute__((ext_vector_type(4))) float f32x4;
typedef __attribute__((ext_vector_type(16))) float f32x16;
typedef __attribute__((ext_vector_type(4))) float float4v;
typedef __attribute__((ext_vector_type(4))) int int4v;

typedef __attribute__((address_space(1))) void g_void;
typedef __attribute__((address_space(3))) void l_void;

__device__ __forceinline__ unsigned short f2bf(float f) {
  union { float f; unsigned int u; } v; v.f = f;
  unsigned int r = v.u + 0x7FFFu + ((v.u >> 16) & 1u);  // round-to-nearest-even
  return (unsigned short)(r >> 16);
}

__device__ __forceinline__ void async_copy16(const void* g, void* l) {
  __builtin_amdgcn_global_load_lds((const g_void*)g, (l_void*)l, 16, 0, 0);
}

// barrier that the compiler cannot move LDS ops across, WITHOUT the
// vmcnt(0)+lgkmcnt(0) drain __syncthreads() forces.
__device__ __forceinline__ void wg_barrier() {
  asm volatile("" ::: "memory");
  __builtin_amdgcn_s_barrier();
  asm volatile("" ::: "memory");
}

#define WAIT_VMCNT(N) asm volatile("s_waitcnt vmcnt(" #N ")" ::: "memory")

// ---- conversion: X fp32->bf16 and W int32*scale->bf16, grid-stride --------
__global__ __launch_bounds__(256) void cvt_kernel(
    const float* __restrict__ x, const int* __restrict__ w,
    const float* __restrict__ s, unsigned short* __restrict__ ox,
    unsigned short* __restrict__ ow, int n8x, int n8w, int gx) {
  if ((int)blockIdx.x < gx) {
    const int stride = gx * 256;
    for (int t = blockIdx.x * 256 + threadIdx.x; t < n8x; t += stride) {
      const float4v* xp = (const float4v*)x + (size_t)t * 2;
      float4v a = xp[0], b = xp[1];
      ushort8 r;
      r[0] = f2bf(a[0]); r[1] = f2bf(a[1]); r[2] = f2bf(a[2]); r[3] = f2bf(a[3]);
      r[4] = f2bf(b[0]); r[5] = f2bf(b[1]); r[6] = f2bf(b[2]); r[7] = f2bf(b[3]);
      *(ushort8*)(ox + (size_t)t * 8) = r;
    }
  } else {
    const int stride = ((int)gridDim.x - gx) * 256;
    for (int t = ((int)blockIdx.x - gx) * 256 + threadIdx.x; t < n8w; t += stride) {
      const int4v* wp = (const int4v*)w + (size_t)t * 2;
      int4v q0 = wp[0], q1 = wp[1];
      float sc = s[t >> 3];  // GROUP_SIZE=64 = 8 threads x 8 elems
      ushort8 r;
      r[0] = f2bf((float)q0[0] * sc); r[1] = f2bf((float)q0[1] * sc);
      r[2] = f2bf((float)q0[2] * sc); r[3] = f2bf((float)q0[3] * sc);
      r[4] = f2bf((float)q1[0] * sc); r[5] = f2bf((float)q1[1] * sc);
      r[6] = f2bf((float)q1[2] * sc); r[7] = f2bf((float)q1[3] * sc);
      *(ushort8*)(ow + (size_t)t * 8) = r;
    }
  }
}

// ---- main GEMM: 256x256 tile, BK=64, 8 waves, 32x32x16 MFMA, 2-phase ------
// LDS (128 KiB): A bufs at 0, B at 64K; buffer p at +p*32K; unit kh at
// +kh*16K. Unit internal layout: [ks(2)][row(256)][chunk(2)x16B], i.e.
// byte = ks*8192 + row*32 + pc*16, where pc = kg ^ ((row>>2)&1) and the
// logical content of (ks,row,pc) is elements k = ks*16 + kg*8 .. +8 of row.
// Write side (global_load_lds, linear): thread tid owns chunks tid (ks0)
// and tid+512 (ks1): row = tid>>1, pc = tid&1 -> kg = (tid&1)^((tid>>3)&1).

#define MF32(a, b, c) __builtin_amdgcn_mfma_f32_32x32x16_bf16(a, b, c, 0, 0, 0)

// 12 ds_read_b128 from one (A,B) kh-unit pair: A 4 m-subtiles x 2 ks,
// B 2 n-subtiles x 2 ks. Each read = contiguous-1KiB permutation.
#define READ12(AU, BU) do {                              \
    const unsigned char* _a = (AU) + abase;              \
    const unsigned char* _b = (BU) + bbase;              \
    a00 = *(const short8*)(_a + cak);                    \
    a10 = *(const short8*)(_a + 1024 + cak);             \
    a20 = *(const short8*)(_a + 2048 + cak);             \
    a30 = *(const short8*)(_a + 3072 + cak);             \
    a01 = *(const short8*)(_a + 8192 + cak);             \
    a11 = *(const short8*)(_a + 8192 + 1024 + cak);      \
    a21 = *(const short8*)(_a + 8192 + 2048 + cak);      \
    a31 = *(const short8*)(_a + 8192 + 3072 + cak);      \
    b00 = *(const short8*)(_b + cak);                    \
    b10 = *(const short8*)(_b + 1024 + cak);             \
    b01 = *(const short8*)(_b + 8192 + cak);             \
    b11 = *(const short8*)(_b + 8192 + 1024 + cak);      \
  } while (0)

// 16 MFMA: ks0 for all 8 (m,n) tiles, then ks1 (dep distance 8 per acc)
#define MFMA16() do {                                    \
    acc[0][0] = MF32(a00, b00, acc[0][0]);               \
    acc[1][0] = MF32(a10, b00, acc[1][0]);               \
    acc[2][0] = MF32(a20, b00, acc[2][0]);               \
    acc[3][0] = MF32(a30, b00, acc[3][0]);               \
    acc[0][1] = MF32(a00, b10, acc[0][1]);               \
    acc[1][1] = MF32(a10, b10, acc[1][1]);               \
    acc[2][1] = MF32(a20, b10, acc[2][1]);               \
    acc[3][1] = MF32(a30, b10, acc[3][1]);               \
    acc[0][0] = MF32(a01, b01, acc[0][0]);               \
    acc[1][0] = MF32(a11, b01, acc[1][0]);               \
    acc[2][0] = MF32(a21, b01, acc[2][0]);               \
    acc[3][0] = MF32(a31, b01, acc[3][0]);               \
    acc[0][1] = MF32(a01, b11, acc[0][1]);               \
    acc[1][1] = MF32(a11, b11, acc[1][1]);               \
    acc[2][1] = MF32(a21, b11, acc[2][1]);               \
    acc[3][1] = MF32(a31, b11, acc[3][1]);               \
  } while (0)

#define PRIO1 __builtin_amdgcn_s_setprio(1)
#define PRIO0 __builtin_amdgcn_s_setprio(0)

// stage one (op,kh) 16KiB unit: 2 global_load_lds per thread
// src = element (row_g)*K + kbase + kg*8; ks0 chunk at src, ks1 at src+16
__device__ __forceinline__ void stage_unit(const unsigned short* src,
                                           unsigned char* dst_unit) {
  async_copy16(src, dst_unit);              // ks=0 chunk
  async_copy16(src + 16, dst_unit + 8192);  // ks=1 chunk
}

__global__ __launch_bounds__(512, 2) void gemm_8p(
    const unsigned short* __restrict__ Xb,  // bf16 [M][K]
    const unsigned short* __restrict__ Wb,  // bf16 [N][K]
    const float* __restrict__ bias,
    float* __restrict__ C, int M, int N, int K) {
  __shared__ __align__(16) unsigned char smem[131072];
  const int tid = threadIdx.x;
  const int lane = tid & 63, w = tid >> 6;
  const int wm = w >> 2, wn = w & 3;   // 2M x 4N waves, per-wave 128x64
  const int l31 = lane & 31, kg = lane >> 5;

  // T1: XCD-aware bijective swizzle (grid % 8 == 0 guaranteed by host gate)
  const int nbn = N >> 8;
  int bid = blockIdx.x;
  {
    const int nwg = gridDim.x;
    if ((nwg & 7) == 0) bid = (bid & 7) * (nwg >> 3) + (bid >> 3);
  }
  const int m0 = (bid / nbn) << 8;
  const int n0 = (bid % nbn) << 8;

  // fragment read addressing: row = subtile + l31 (subtiles % 32 == 0 so
  // (row>>2)&1 == (l31>>2)&1); phys chunk = kg ^ ((l31>>2)&1)
  const int cak = ((kg ^ ((l31 >> 2) & 1)) << 4);
  const int abase = (wm * 128 + l31) * 32;
  const int bbase = (wn * 64 + l31) * 32;

  // staging: thread tid -> row = tid>>1, pc = tid&1, kg = pc ^ ((row>>2)&1)
  const int rowi = tid >> 1;
  const int kgi = ((tid & 1) ^ ((tid >> 3) & 1)) << 3;  // element offset 0 or 8
  const unsigned short* pA = Xb + (size_t)(m0 + rowi) * K + kgi;
  const unsigned short* pB = Wb + (size_t)(n0 + rowi) * K + kgi;
  const int wuo = w << 10;  // wave-uniform LDS dest offset (lane*16 by HW)

  f32x16 acc[4][2];
#pragma unroll
  for (int i = 0; i < 4; i++)
#pragma unroll
    for (int j = 0; j < 2; j++) acc[i][j] = (f32x16)(0.f);

  const int NT = K >> 6;

  // prologue: stage tile 0 -> buf 0: A-kh0, B-kh0, A-kh1, B-kh1 (8 instrs)
  stage_unit(pA, smem + wuo);
  stage_unit(pB, smem + 65536 + wuo);
  stage_unit(pA + 32, smem + 16384 + wuo);
  stage_unit(pB + 32, smem + 65536 + 16384 + wuo);
  WAIT_VMCNT(4);   // retire kh0 units; kh1 (4 instrs) stays in flight
  wg_barrier();

  short8 a00, a10, a20, a30, a01, a11, a21, a31, b00, b10, b01, b11;

  // invariant entering tile t: 4 outstanding loads = tile t's kh1 units
  for (int t = 0; t < NT - 1; ++t) {
    const int p = t & 1;
    const unsigned char* Au = smem + p * 32768;
    const unsigned char* Bu = smem + 65536 + p * 32768;
    unsigned char* Aq = smem + (p ^ 1) * 32768 + wuo;
    unsigned char* Bq = smem + 65536 + (p ^ 1) * 32768 + wuo;
    const unsigned short* sA = pA + (size_t)(t + 1) * 64;
    const unsigned short* sB = pB + (size_t)(t + 1) * 64;

    // phase 1: kh0 compute | stage kh0(t+1)
    READ12(Au, Bu);
    stage_unit(sA, Aq);
    stage_unit(sB, Bq);
    PRIO1; MFMA16(); PRIO0;
    WAIT_VMCNT(4);   // retire kh1(t), issued one full phase ago
    wg_barrier();
    // phase 2: kh1 compute | stage kh1(t+1)
    READ12(Au + 16384, Bu + 16384);
    stage_unit(sA + 32, Aq + 16384);
    stage_unit(sB + 32, Bq + 16384);
    PRIO1; MFMA16(); PRIO0;
    WAIT_VMCNT(4);   // retire kh0(t+1); its kh1 stays in flight
    wg_barrier();
  }

  // final tile (no staging): entering with its kh1 units still in flight
  {
    const int p = (NT - 1) & 1;
    const unsigned char* Au = smem + p * 32768;
    const unsigned char* Bu = smem + 65536 + p * 32768;
    READ12(Au, Bu);
    PRIO1; MFMA16(); PRIO0;
    WAIT_VMCNT(0);   // drain kh1 units (only non-counted wait in the kernel)
    wg_barrier();
    READ12(Au + 16384, Bu + 16384);
    PRIO1; MFMA16(); PRIO0;
  }

  // epilogue: 32x32 C layout: col = lane&31, row = (r&3) + 8*(r>>2) + 4*kg
  const int gm = m0 + wm * 128 + 4 * kg;
  const int gn = n0 + wn * 64 + l31;
  const float bv0 = bias[gn], bv1 = bias[gn + 32];
#pragma unroll
  for (int mt = 0; mt < 4; ++mt) {
#pragma unroll
    for (int nt = 0; nt < 2; ++nt) {
      const float bv = nt ? bv1 : bv0;
      const int col = gn + nt * 32;
      f32x16 v = acc[mt][nt];
#pragma unroll
      for (int r = 0; r < 16; ++r) {
        const int row = gm + mt * 32 + (r & 3) + 8 * (r >> 2);
        C[(size_t)row * N + col] = v[r] + bv;
      }
    }
  }
}

// ---- fallback: fused dequant GEMM (odd shapes / tiny ws; never bounded) --
#define BM 128
#define BN 128
#define BK 64

__global__ __launch_bounds__(256) void gemm_fused(
    const float* __restrict__ Xf, const int* __restrict__ Wq,
    const float* __restrict__ Ws, const float* __restrict__ bias,
    float* __restrict__ C, int M, int N, int K) {
  __shared__ unsigned char smem[(BM * BK + BN * BK) * 2];
  const int tid = threadIdx.x;
  const int lane = tid & 63, wid = tid >> 6;
  const int m0 = blockIdx.y * BM, n0 = blockIdx.x * BN;
  const int sr = lane >> 3, fc = (lane & 7) ^ sr;
  const int arow = m0 + wid * 32 + sr, brow = n0 + wid * 32 + sr;
  unsigned char* As = smem;
  unsigned char* Bs = smem + BM * BK * 2;
  unsigned char* stA = As + wid * 4096 + lane * 16;
  unsigned char* stB = Bs + wid * 4096 + lane * 16;
  const int l31 = lane & 31, lh = lane >> 5, le = lane & 7;
  const int wm = (wid & 1) * 64, wn = (wid >> 1) * 64;
  const unsigned char* Aw = As + (wm + l31) * 128;
  const unsigned char* Bw = Bs + (wn + l31) * 128;
  const int Kg = K >> 6;

  f32x16 acc[2][2];
#pragma unroll
  for (int i = 0; i < 2; i++)
#pragma unroll
    for (int j = 0; j < 2; j++) acc[i][j] = (f32x16)(0.f);

  for (int k0 = 0; k0 < K; k0 += BK) {
#pragma unroll
    for (int t = 0; t < 4; t++) {
      const float4v* xa = (const float4v*)(Xf + (size_t)(arow + t * 8) * K + k0 + fc * 8);
      float4v x0 = xa[0], x1 = xa[1];
      ushort8 ra;
      ra[0] = f2bf(x0[0]); ra[1] = f2bf(x0[1]); ra[2] = f2bf(x0[2]); ra[3] = f2bf(x0[3]);
      ra[4] = f2bf(x1[0]); ra[5] = f2bf(x1[1]); ra[6] = f2bf(x1[2]); ra[7] = f2bf(x1[3]);
      *(ushort8*)(stA + t * 1024) = ra;
      const int4v* wq = (const int4v*)(Wq + (size_t)(brow + t * 8) * K + k0 + fc * 8);
      int4v q0 = wq[0], q1 = wq[1];
      float sc = Ws[(size_t)(brow + t * 8) * Kg + (k0 >> 6)];
      ushort8 rb;
      rb[0] = f2bf((float)q0[0] * sc); rb[1] = f2bf((float)q0[1] * sc);
      rb[2] = f2bf((float)q0[2] * sc); rb[3] = f2bf((float)q0[3] * sc);
      rb[4] = f2bf((float)q1[0] * sc); rb[5] = f2bf((float)q1[1] * sc);
      rb[6] = f2bf((float)q1[2] * sc); rb[7] = f2bf((float)q1[3] * sc);
      *(ushort8*)(stB + t * 1024) = rb;
    }
    __syncthreads();
#pragma unroll
    for (int s = 0; s < 4; s++) {
      const int off = ((s + 4 * lh) ^ le) << 4;
      short8 a0 = *(const short8*)(Aw + off);
      short8 a1 = *(const short8*)(Aw + 4096 + off);
      short8 b0 = *(const short8*)(Bw + off);
      short8 b1 = *(const short8*)(Bw + 4096 + off);
      acc[0][0] = __builtin_amdgcn_mfma_f32_32x32x16_bf16(a0, b0, acc[0][0], 0, 0, 0);
      acc[0][1] = __builtin_amdgcn_mfma_f32_32x32x16_bf16(a0, b1, acc[0][1], 0, 0, 0);
      acc[1][0] = __builtin_amdgcn_mfma_f32_32x32x16_bf16(a1, b0, acc[1][0], 0, 0, 0);
      acc[1][1] = __builtin_amdgcn_mfma_f32_32x32x16_bf16(a1, b1, acc[1][1], 0, 0, 0);
    }
    __syncthreads();
  }

  const int gm = m0 + wm + 4 * lh, gn = n0 + wn + l31;
#pragma unroll
  for (int j = 0; j < 2; j++) {
    const int col = gn + j * 32;
    const float bv = bias[col];
#pragma unroll
    for (int i = 0; i < 2; i++) {
      const int rbase = gm + i * 32;
      f32x16 v = acc[i][j];
#pragma unroll
      for (int r = 0; r < 16; r++) {
        const int row = rbase + (r & 3) + 8 * (r >> 2);
        C[(size_t)row * N + col] = v[r] + bv;
      }
    }
  }
}

extern "C" void kernel_launch(void* const* d_in, const int* in_sizes, int n_in,
                              void* d_out, int out_size, void* d_ws, size_t ws_size,
                              hipStream_t stream) {
  const float* x = (const float*)d_in[0];
  const int* wq = (const int*)d_in[1];
  const float* wsc = (const float*)d_in[2];
  const float* bias = (const float*)d_in[3];
  float* out = (float*)d_out;

  const int N = in_sizes[3];            // D_out (bias length)
  const int K = in_sizes[1] / N;        // D_in
  const int M = in_sizes[0] / K;        // B*S

  const size_t needX = (size_t)M * K * 2;
  const size_t needW = (size_t)N * K * 2;
  const bool big = (M % 256 == 0) && (N % 256 == 0) && (K % 64 == 0) && (K >= 128);

  if (big && ws_size >= needX + needW) {
    unsigned short* Xb = (unsigned short*)d_ws;
    unsigned short* Wb = (unsigned short*)((char*)d_ws + needX);
    const int n8x = (M * K) / 8, n8w = (N * K) / 8;
    // grid-stride cvt: ~8 blocks/CU, X:W work ratio = 2:1
    const int gx = 1376, gw = 688;
    cvt_kernel<<<gx + gw, 256, 0, stream>>>(x, wq, wsc, Xb, Wb, n8x, n8w, gx);
    dim3 grid((M / 256) * (N / 256));
    gemm_8p<<<grid, 512, 0, stream>>>(Xb, Wb, bias, out, M, N, K);
  } else {
    dim3 grid(N / BN, M / BM), block(256);
    gemm_fused<<<grid, block, 0, stream>>>(x, wq, wsc, bias, out, M, N, K);
  }
}

// Round 4
// 540.779 us; speedup vs baseline: 1.0721x; 1.0573x over previous
//
#include <hip/hip_runtime.h>
#include <stdint.h>

// GEMM: C[M,N] = X[M,K] * W[N,K]^T + bias, group-dequantized W (group=64 along K).
// R8: occupancy-first redesign. Empirical rule from R0/R5/R6/R7 counters:
// 32-row (l31) b128 LDS reads cost exactly 4 conflict-cyc/read regardless of
// layout; 16-row (l15) reads are free -> keep R5's 16x16x32 read pattern.
// R5's 49% util gap is structural: 1 block/CU (230 regs/wave: 128 acc + ~100
// arch) alternates LDS-read and MFMA bursts with nobody to overlap. Fix:
// wave tile 64x64 (acc 64 regs, ~115 total), BM=128/BN=256/BK=32, LDS 48KB,
// __launch_bounds__(512,4) -> 2 blocks/CU; sibling block covers read/sync
// intervals. Sync: ONE barrier + one vmcnt(0) per 32-k tile (reads complete
// via lgkmcnt before MFMA, stages into a buffer only start one barrier after
// its last read; vmcnt(0) retires own loads issued a full phase earlier).

typedef __attribute__((ext_vector_type(8))) short short8;       // 8 bf16 = 4 VGPRs
typedef __attribute__((ext_vector_type(8))) unsigned short ushort8;
typedef __attribute__((ext_vector_type(4))) float f32x4;
typedef __attribute__((ext_vector_type(16))) float f32x16;
typedef __attribute__((ext_vector_type(4))) float float4v;
typedef __attribute__((ext_vector_type(4))) int int4v;

typedef __attribute__((address_space(1))) void g_void;
typedef __attribute__((address_space(3))) void l_void;

__device__ __forceinline__ unsigned short f2bf(float f) {
  union { float f; unsigned int u; } v; v.f = f;
  unsigned int r = v.u + 0x7FFFu + ((v.u >> 16) & 1u);  // round-to-nearest-even
  return (unsigned short)(r >> 16);
}

__device__ __forceinline__ void async_copy16(const void* g, void* l) {
  __builtin_amdgcn_global_load_lds((const g_void*)g, (l_void*)l, 16, 0, 0);
}

// barrier that the compiler cannot move LDS ops across, WITHOUT the
// vmcnt(0)+lgkmcnt(0) drain __syncthreads() forces.
__device__ __forceinline__ void wg_barrier() {
  asm volatile("" ::: "memory");
  __builtin_amdgcn_s_barrier();
  asm volatile("" ::: "memory");
}

#define WAIT_VMCNT(N) asm volatile("s_waitcnt vmcnt(" #N ")" ::: "memory")

// ---- conversion: X fp32->bf16 and W int32*scale->bf16, grid-stride --------
__global__ __launch_bounds__(256) void cvt_kernel(
    const float* __restrict__ x, const int* __restrict__ w,
    const float* __restrict__ s, unsigned short* __restrict__ ox,
    unsigned short* __restrict__ ow, int n8x, int n8w, int gx) {
  if ((int)blockIdx.x < gx) {
    const int stride = gx * 256;
    for (int t = blockIdx.x * 256 + threadIdx.x; t < n8x; t += stride) {
      const float4v* xp = (const float4v*)x + (size_t)t * 2;
      float4v a = xp[0], b = xp[1];
      ushort8 r;
      r[0] = f2bf(a[0]); r[1] = f2bf(a[1]); r[2] = f2bf(a[2]); r[3] = f2bf(a[3]);
      r[4] = f2bf(b[0]); r[5] = f2bf(b[1]); r[6] = f2bf(b[2]); r[7] = f2bf(b[3]);
      *(ushort8*)(ox + (size_t)t * 8) = r;
    }
  } else {
    const int stride = ((int)gridDim.x - gx) * 256;
    for (int t = ((int)blockIdx.x - gx) * 256 + threadIdx.x; t < n8w; t += stride) {
      const int4v* wp = (const int4v*)w + (size_t)t * 2;
      int4v q0 = wp[0], q1 = wp[1];
      float sc = s[t >> 3];  // GROUP_SIZE=64 = 8 threads x 8 elems
      ushort8 r;
      r[0] = f2bf((float)q0[0] * sc); r[1] = f2bf((float)q0[1] * sc);
      r[2] = f2bf((float)q0[2] * sc); r[3] = f2bf((float)q0[3] * sc);
      r[4] = f2bf((float)q1[0] * sc); r[5] = f2bf((float)q1[1] * sc);
      r[6] = f2bf((float)q1[2] * sc); r[7] = f2bf((float)q1[3] * sc);
      *(ushort8*)(ow + (size_t)t * 8) = r;
    }
  }
}

// ---- main GEMM: 128x256 tile, BK=32, 8 waves (2m x 4n, 64x64 each) --------
// LDS (48 KiB): A bufs [2][128 rows][64 B] at 0..16K; B bufs [2][256][64B]
// at 16K..48K. Row = 64 B = 4 chunks of 16 B (32 k). Phys chunk of row r
// holds logical chunk pc ^ ((r>>1)&3) (R5's verified conflict-free scheme;
// inverse folded into per-lane global source since global_load_lds dests
// are linear: dest byte = tid*16 -> row = tid>>2, pc = tid&3).

#define MF16(a, b, c) __builtin_amdgcn_mfma_f32_16x16x32_bf16(a, b, c, 0, 0, 0)

#define LDA(base) do {                                  \
    const unsigned char* _p = (base) + aoff;            \
    av0 = *(const short8*)(_p);                         \
    av1 = *(const short8*)(_p + 1024);                  \
    av2 = *(const short8*)(_p + 2048);                  \
    av3 = *(const short8*)(_p + 3072);                  \
  } while (0)

#define LDB(base) do {                                  \
    const unsigned char* _p = (base) + boff;            \
    bv0 = *(const short8*)(_p);                         \
    bv1 = *(const short8*)(_p + 1024);                  \
    bv2 = *(const short8*)(_p + 2048);                  \
    bv3 = *(const short8*)(_p + 3072);                  \
  } while (0)

#define MM16() do {                                     \
    acc[0][0] = MF16(av0, bv0, acc[0][0]);              \
    acc[0][1] = MF16(av0, bv1, acc[0][1]);              \
    acc[0][2] = MF16(av0, bv2, acc[0][2]);              \
    acc[0][3] = MF16(av0, bv3, acc[0][3]);              \
    acc[1][0] = MF16(av1, bv0, acc[1][0]);              \
    acc[1][1] = MF16(av1, bv1, acc[1][1]);              \
    acc[1][2] = MF16(av1, bv2, acc[1][2]);              \
    acc[1][3] = MF16(av1, bv3, acc[1][3]);              \
    acc[2][0] = MF16(av2, bv0, acc[2][0]);              \
    acc[2][1] = MF16(av2, bv1, acc[2][1]);              \
    acc[2][2] = MF16(av2, bv2, acc[2][2]);              \
    acc[2][3] = MF16(av2, bv3, acc[2][3]);              \
    acc[3][0] = MF16(av3, bv0, acc[3][0]);              \
    acc[3][1] = MF16(av3, bv1, acc[3][1]);              \
    acc[3][2] = MF16(av3, bv2, acc[3][2]);              \
    acc[3][3] = MF16(av3, bv3, acc[3][3]);              \
  } while (0)

#define PRIO1 __builtin_amdgcn_s_setprio(1)
#define PRIO0 __builtin_amdgcn_s_setprio(0)

// stage a 256-row unit (B): 2 loads; rows [0,128) and [128,256)
__device__ __forceinline__ void stage2(const unsigned short* src, int rstride,
                                       unsigned char* dst) {
  async_copy16(src, dst);
  async_copy16(src + rstride, dst + 8192);
}

// one K-tile: stage next tile's units into (Aq,Bq), compute from (Au,Bu).
// 1 barrier + 1 vmcnt(0) per tile; reads of Au/Bu are consumed (lgkmcnt
// enforced by MFMA operands) before the barrier, so next tile's stage into
// the same buffer (issued after the NEXT barrier) cannot race them.
#define TILE(Au, Bu, Aq, Bq, koff) do {                 \
    async_copy16(pA + (koff), Aq);                      \
    stage2(pB + (koff), rstride, Bq);                   \
    LDA(Au); LDB(Bu);                                   \
    PRIO1; MM16(); PRIO0;                               \
    WAIT_VMCNT(0);                                      \
    wg_barrier();                                       \
  } while (0)

__global__ __launch_bounds__(512, 4) void gemm_8p(
    const unsigned short* __restrict__ Xb,  // bf16 [M][K]
    const unsigned short* __restrict__ Wb,  // bf16 [N][K]
    const float* __restrict__ bias,
    float* __restrict__ C, int M, int N, int K) {
  __shared__ __align__(16) unsigned char smem[49152];
  const int tid = threadIdx.x;
  const int lane = tid & 63, w = tid >> 6;
  const int wm = w >> 2, wn = w & 3;   // 2M x 4N waves, 64x64 each
  const int l15 = lane & 15;

  // T1: XCD-aware bijective swizzle (grid % 8 == 0 guaranteed by host gate)
  const int nbn = N >> 8;
  int bid = blockIdx.x;
  {
    const int nwg = gridDim.x;
    if ((nwg & 7) == 0) bid = (bid & 7) * (nwg >> 3) + (bid >> 3);
  }
  const int m0 = (bid / nbn) << 7;   // 128-row tiles
  const int n0 = (bid % nbn) << 8;   // 256-col tiles

  // fragment reads: row = msub*16 + l15, logical chunk = lane>>4,
  // phys = (lane>>4) ^ ((row>>1)&3) = (lane>>4) ^ ((l15>>1)&3)
  const int chnk = (((lane >> 4) ^ ((l15 >> 1) & 3)) << 4);
  const int aoff = (wm * 64 + l15) * 64 + chnk;
  const int boff = (wn * 64 + l15) * 64 + chnk;

  // staging: thread tid -> row = tid>>2, phys chunk = tid&3,
  // logical chunk = (tid&3) ^ ((row>>1)&3) = (tid&3) ^ ((tid>>3)&3)
  const int rl = tid >> 2;
  const int lc = (tid & 3) ^ ((tid >> 3) & 3);
  const unsigned short* pA = Xb + (size_t)(m0 + rl) * K + lc * 8;
  const unsigned short* pB = Wb + (size_t)(n0 + rl) * K + lc * 8;
  const int rstride = K << 7;   // 128 rows in elements
  const int wuo = w << 10;      // wave-uniform LDS dest (HW adds lane*16)

  // LDS pointers: A buf p @ p*8192 (8KB units); B @ 16384 + p*16384
  const unsigned char* A0 = smem;
  const unsigned char* A1 = smem + 8192;
  const unsigned char* B0 = smem + 16384;
  const unsigned char* B1 = smem + 32768;
  unsigned char* A0q = smem + wuo;
  unsigned char* A1q = smem + 8192 + wuo;
  unsigned char* B0q = smem + 16384 + wuo;
  unsigned char* B1q = smem + 32768 + wuo;

  f32x4 acc[4][4];
#pragma unroll
  for (int i = 0; i < 4; i++)
#pragma unroll
    for (int j = 0; j < 4; j++) acc[i][j] = (f32x4)(0.f);

  const int NT = K >> 5;   // 32-k tiles; even (K % 64 == 0 gated on host)

  // prologue: stage tile 0 -> buf 0 (3 loads), drain, publish
  async_copy16(pA, A0q);
  stage2(pB, rstride, B0q);
  WAIT_VMCNT(0);
  wg_barrier();

  short8 av0, av1, av2, av3, bv0, bv1, bv2, bv3;

  // 2-tile unrolled main loop: tiles 2i (buf0) and 2i+1 (buf1)
  for (int t2 = 0; t2 < (NT >> 1) - 1; ++t2) {
    const int koff = t2 * 64 + 32;            // element offset of tile 2i+1
    TILE(A0, B0, A1q, B1q, koff);             // compute 2i, stage 2i+1
    TILE(A1, B1, A0q, B0q, koff + 32);        // compute 2i+1, stage 2i+2
  }
  // tile NT-2 (buf0): stage NT-1 -> buf1
  TILE(A0, B0, A1q, B1q, (NT - 1) * 32);
  // tile NT-1 (buf1): no stage, nothing outstanding
  LDA(A1); LDB(B1);
  PRIO1; MM16(); PRIO0;

  // epilogue: 16x16x32 C layout: col = lane&15, row = (lane>>4)*4 + reg
  const int gm = m0 + wm * 64 + ((lane >> 4) << 2);
  const int gn = n0 + wn * 64 + l15;
  float bvs[4];
#pragma unroll
  for (int g = 0; g < 4; ++g) bvs[g] = bias[gn + g * 16];
#pragma unroll
  for (int mt = 0; mt < 4; ++mt) {
    const size_t rb = (size_t)(gm + mt * 16) * N + gn;
#pragma unroll
    for (int r = 0; r < 4; ++r) {
#pragma unroll
      for (int nt = 0; nt < 4; ++nt)
        C[rb + (size_t)r * N + nt * 16] = acc[mt][nt][r] + bvs[nt];
    }
  }
}

// ---- fallback: fused dequant GEMM (odd shapes / tiny ws; never bounded) --
#define BM 128
#define BN 128
#define BK 64

__global__ __launch_bounds__(256) void gemm_fused(
    const float* __restrict__ Xf, const int* __restrict__ Wq,
    const float* __restrict__ Ws, const float* __restrict__ bias,
    float* __restrict__ C, int M, int N, int K) {
  __shared__ unsigned char smem[(BM * BK + BN * BK) * 2];
  const int tid = threadIdx.x;
  const int lane = tid & 63, wid = tid >> 6;
  const int m0 = blockIdx.y * BM, n0 = blockIdx.x * BN;
  const int sr = lane >> 3, fc = (lane & 7) ^ sr;
  const int arow = m0 + wid * 32 + sr, brow = n0 + wid * 32 + sr;
  unsigned char* As = smem;
  unsigned char* Bs = smem + BM * BK * 2;
  unsigned char* stA = As + wid * 4096 + lane * 16;
  unsigned char* stB = Bs + wid * 4096 + lane * 16;
  const int l31 = lane & 31, lh = lane >> 5, le = lane & 7;
  const int wm = (wid & 1) * 64, wn = (wid >> 1) * 64;
  const unsigned char* Aw = As + (wm + l31) * 128;
  const unsigned char* Bw = Bs + (wn + l31) * 128;
  const int Kg = K >> 6;

  f32x16 acc[2][2];
#pragma unroll
  for (int i = 0; i < 2; i++)
#pragma unroll
    for (int j = 0; j < 2; j++) acc[i][j] = (f32x16)(0.f);

  for (int k0 = 0; k0 < K; k0 += BK) {
#pragma unroll
    for (int t = 0; t < 4; t++) {
      const float4v* xa = (const float4v*)(Xf + (size_t)(arow + t * 8) * K + k0 + fc * 8);
      float4v x0 = xa[0], x1 = xa[1];
      ushort8 ra;
      ra[0] = f2bf(x0[0]); ra[1] = f2bf(x0[1]); ra[2] = f2bf(x0[2]); ra[3] = f2bf(x0[3]);
      ra[4] = f2bf(x1[0]); ra[5] = f2bf(x1[1]); ra[6] = f2bf(x1[2]); ra[7] = f2bf(x1[3]);
      *(ushort8*)(stA + t * 1024) = ra;
      const int4v* wq = (const int4v*)(Wq + (size_t)(brow + t * 8) * K + k0 + fc * 8);
      int4v q0 = wq[0], q1 = wq[1];
      float sc = Ws[(size_t)(brow + t * 8) * Kg + (k0 >> 6)];
      ushort8 rb;
      rb[0] = f2bf((float)q0[0] * sc); rb[1] = f2bf((float)q0[1] * sc);
      rb[2] = f2bf((float)q0[2] * sc); rb[3] = f2bf((float)q0[3] * sc);
      rb[4] = f2bf((float)q1[0] * sc); rb[5] = f2bf((float)q1[1] * sc);
      rb[6] = f2bf((float)q1[2] * sc); rb[7] = f2bf((float)q1[3] * sc);
      *(ushort8*)(stB + t * 1024) = rb;
    }
    __syncthreads();
#pragma unroll
    for (int s = 0; s < 4; s++) {
      const int off = ((s + 4 * lh) ^ le) << 4;
      short8 a0 = *(const short8*)(Aw + off);
      short8 a1 = *(const short8*)(Aw + 4096 + off);
      short8 b0 = *(const short8*)(Bw + off);
      short8 b1 = *(const short8*)(Bw + 4096 + off);
      acc[0][0] = __builtin_amdgcn_mfma_f32_32x32x16_bf16(a0, b0, acc[0][0], 0, 0, 0);
      acc[0][1] = __builtin_amdgcn_mfma_f32_32x32x16_bf16(a0, b1, acc[0][1], 0, 0, 0);
      acc[1][0] = __builtin_amdgcn_mfma_f32_32x32x16_bf16(a1, b0, acc[1][0], 0, 0, 0);
      acc[1][1] = __builtin_amdgcn_mfma_f32_32x32x16_bf16(a1, b1, acc[1][1], 0, 0, 0);
    }
    __syncthreads();
  }

  const int gm = m0 + wm + 4 * lh, gn = n0 + wn + l31;
#pragma unroll
  for (int j = 0; j < 2; j++) {
    const int col = gn + j * 32;
    const float bv = bias[col];
#pragma unroll
    for (int i = 0; i < 2; i++) {
      const int rbase = gm + i * 32;
      f32x16 v = acc[i][j];
#pragma unroll
      for (int r = 0; r < 16; r++) {
        const int row = rbase + (r & 3) + 8 * (r >> 2);
        C[(size_t)row * N + col] = v[r] + bv;
      }
    }
  }
}

extern "C" void kernel_launch(void* const* d_in, const int* in_sizes, int n_in,
                              void* d_out, int out_size, void* d_ws, size_t ws_size,
                              hipStream_t stream) {
  const float* x = (const float*)d_in[0];
  const int* wq = (const int*)d_in[1];
  const float* wsc = (const float*)d_in[2];
  const float* bias = (const float*)d_in[3];
  float* out = (float*)d_out;

  const int N = in_sizes[3];            // D_out (bias length)
  const int K = in_sizes[1] / N;        // D_in
  const int M = in_sizes[0] / K;        // B*S

  const size_t needX = (size_t)M * K * 2;
  const size_t needW = (size_t)N * K * 2;
  const bool big = (M % 128 == 0) && (N % 256 == 0) && (K % 64 == 0) && (K >= 128);

  if (big && ws_size >= needX + needW) {
    unsigned short* Xb = (unsigned short*)d_ws;
    unsigned short* Wb = (unsigned short*)((char*)d_ws + needX);
    const int n8x = (M * K) / 8, n8w = (N * K) / 8;
    // grid-stride cvt: ~8 blocks/CU, X:W work ratio = 2:1
    const int gx = 1376, gw = 688;
    cvt_kernel<<<gx + gw, 256, 0, stream>>>(x, wq, wsc, Xb, Wb, n8x, n8w, gx);
    dim3 grid((M / 128) * (N / 256));
    gemm_8p<<<grid, 512, 0, stream>>>(Xb, Wb, bias, out, M, N, K);
  } else {
    dim3 grid(N / BN, M / BM), block(256);
    gemm_fused<<<grid, block, 0, stream>>>(x, wq, wsc, bias, out, M, N, K);
  }
}

// Round 6
// 518.146 us; speedup vs baseline: 1.1189x; 1.0437x over previous
//
#include <hip/hip_runtime.h>
#include <stdint.h>

// GEMM: C[M,N] = X[M,K] * W[N,K]^T + bias, group-dequantized W (group=64 along K).
// R9 (resubmit; R5 run hit an infra "container failed twice" error, no data).
// R5 base (252us best; 16x16x32 frags, l15-row reads = 0 conflicts) with ONE
// change: m201-depth staging. R8 proved pipeline depth > occupancy (2 blk/CU
// with same-tile vmcnt(0) regressed to 296us). Schedule keeps 3 half-tiles
// issued ahead / 2 in flight after each wait:
//   tile t ph1: stage A-kh1(t+1)   ph2: stage B-kh1(t+1), WAIT vmcnt(8)
//   tile t ph3: stage A-kh0(t+2)   ph4: stage B-kh0(t+2), WAIT vmcnt(8)
// Issue-to-retire ~5 phases (vs R5's 2-3). Race-check: kh1(t+1) writes go to
// buf p^1 whose kh1 readers (tile t-1 ph3-4) are barrier-separated; kh0(t+2)
// writes go to buf p AFTER the ph2 barrier that ends tile t's kh0 reads.
// Uniform vmcnt(8) both waits (12 outstanding -> 8). Epilogue peels NT-2
// (waits 8,4) and NT-1 (wait 0). vmcnt ledger + race audit re-verified R5->R9.

typedef __attribute__((ext_vector_type(8))) short short8;       // 8 bf16 = 4 VGPRs
typedef __attribute__((ext_vector_type(8))) unsigned short ushort8;
typedef __attribute__((ext_vector_type(4))) float f32x4;
typedef __attribute__((ext_vector_type(16))) float f32x16;
typedef __attribute__((ext_vector_type(4))) float float4v;
typedef __attribute__((ext_vector_type(4))) int int4v;

typedef __attribute__((address_space(1))) void g_void;
typedef __attribute__((address_space(3))) void l_void;

__device__ __forceinline__ unsigned short f2bf(float f) {
  union { float f; unsigned int u; } v; v.f = f;
  unsigned int r = v.u + 0x7FFFu + ((v.u >> 16) & 1u);  // round-to-nearest-even
  return (unsigned short)(r >> 16);
}

__device__ __forceinline__ void async_copy16(const void* g, void* l) {
  __builtin_amdgcn_global_load_lds((const g_void*)g, (l_void*)l, 16, 0, 0);
}

// barrier that the compiler cannot move LDS ops across, WITHOUT the
// vmcnt(0)+lgkmcnt(0) drain __syncthreads() forces.
__device__ __forceinline__ void wg_barrier() {
  asm volatile("" ::: "memory");
  __builtin_amdgcn_s_barrier();
  asm volatile("" ::: "memory");
}

#define WAIT_VMCNT(N) asm volatile("s_waitcnt vmcnt(" #N ")" ::: "memory")

// ---- conversion: X fp32->bf16 and W int32*scale->bf16, grid-stride --------
__global__ __launch_bounds__(256) void cvt_kernel(
    const float* __restrict__ x, const int* __restrict__ w,
    const float* __restrict__ s, unsigned short* __restrict__ ox,
    unsigned short* __restrict__ ow, int n8x, int n8w, int gx) {
  if ((int)blockIdx.x < gx) {
    const int stride = gx * 256;
    for (int t = blockIdx.x * 256 + threadIdx.x; t < n8x; t += stride) {
      const float4v* xp = (const float4v*)x + (size_t)t * 2;
      float4v a = xp[0], b = xp[1];
      ushort8 r;
      r[0] = f2bf(a[0]); r[1] = f2bf(a[1]); r[2] = f2bf(a[2]); r[3] = f2bf(a[3]);
      r[4] = f2bf(b[0]); r[5] = f2bf(b[1]); r[6] = f2bf(b[2]); r[7] = f2bf(b[3]);
      *(ushort8*)(ox + (size_t)t * 8) = r;
    }
  } else {
    const int stride = ((int)gridDim.x - gx) * 256;
    for (int t = ((int)blockIdx.x - gx) * 256 + threadIdx.x; t < n8w; t += stride) {
      const int4v* wp = (const int4v*)w + (size_t)t * 2;
      int4v q0 = wp[0], q1 = wp[1];
      float sc = s[t >> 3];  // GROUP_SIZE=64 = 8 threads x 8 elems
      ushort8 r;
      r[0] = f2bf((float)q0[0] * sc); r[1] = f2bf((float)q0[1] * sc);
      r[2] = f2bf((float)q0[2] * sc); r[3] = f2bf((float)q0[3] * sc);
      r[4] = f2bf((float)q1[0] * sc); r[5] = f2bf((float)q1[1] * sc);
      r[6] = f2bf((float)q1[2] * sc); r[7] = f2bf((float)q1[3] * sc);
      *(ushort8*)(ow + (size_t)t * 8) = r;
    }
  }
}

// ---- main GEMM: 256x256 tile, BK=64, 8 waves, 4-phase, depth-3 staging ----
// LDS (128 KiB): A bufs [2][2kh][256 rows][32 k] at 0..64K, B same at 64K..128K.
// Unit = one (buf,op,kh) slab of 16 KiB, staged by 2 global_load_lds/thread.
// Chunk swizzle: physical 16B chunk pc holds logical chunk pc ^ ((row>>1)&3)
// (involution; applied to the per-lane GLOBAL source on the write side since
// global_load_lds dests are linear, and to the ds_read address on the read
// side). Fragment reads (rows via l15) land 2 lanes/bank = conflict-free
// (R5 measured: SQ_LDS_BANK_CONFLICT == 0).

#define MF(a, b, c) __builtin_amdgcn_mfma_f32_16x16x32_bf16(a, b, c, 0, 0, 0)

#define LDA(base, mh) do {                              \
    const unsigned char* _p = (base) + aoff + (mh) * 4096; \
    av0 = *(const short8*)(_p);                         \
    av1 = *(const short8*)(_p + 1024);                  \
    av2 = *(const short8*)(_p + 2048);                  \
    av3 = *(const short8*)(_p + 3072);                  \
  } while (0)

#define LDB(base) do {                                  \
    const unsigned char* _p = (base) + boff;            \
    bv0 = *(const short8*)(_p);                         \
    bv1 = *(const short8*)(_p + 1024);                  \
    bv2 = *(const short8*)(_p + 2048);                  \
    bv3 = *(const short8*)(_p + 3072);                  \
  } while (0)

#define MM16(mb) do {                                           \
    acc[(mb)+0][0] = MF(av0, bv0, acc[(mb)+0][0]);              \
    acc[(mb)+0][1] = MF(av0, bv1, acc[(mb)+0][1]);              \
    acc[(mb)+0][2] = MF(av0, bv2, acc[(mb)+0][2]);              \
    acc[(mb)+0][3] = MF(av0, bv3, acc[(mb)+0][3]);              \
    acc[(mb)+1][0] = MF(av1, bv0, acc[(mb)+1][0]);              \
    acc[(mb)+1][1] = MF(av1, bv1, acc[(mb)+1][1]);              \
    acc[(mb)+1][2] = MF(av1, bv2, acc[(mb)+1][2]);              \
    acc[(mb)+1][3] = MF(av1, bv3, acc[(mb)+1][3]);              \
    acc[(mb)+2][0] = MF(av2, bv0, acc[(mb)+2][0]);              \
    acc[(mb)+2][1] = MF(av2, bv1, acc[(mb)+2][1]);              \
    acc[(mb)+2][2] = MF(av2, bv2, acc[(mb)+2][2]);              \
    acc[(mb)+2][3] = MF(av2, bv3, acc[(mb)+2][3]);              \
    acc[(mb)+3][0] = MF(av3, bv0, acc[(mb)+3][0]);              \
    acc[(mb)+3][1] = MF(av3, bv1, acc[(mb)+3][1]);              \
    acc[(mb)+3][2] = MF(av3, bv2, acc[(mb)+3][2]);              \
    acc[(mb)+3][3] = MF(av3, bv3, acc[(mb)+3][3]);              \
  } while (0)

#define PRIO1 __builtin_amdgcn_s_setprio(1)
#define PRIO0 __builtin_amdgcn_s_setprio(0)

__device__ __forceinline__ void stage2(const unsigned short* src, int rstride,
                                       unsigned char* dst) {
  async_copy16(src, dst);                    // rows [0,128)
  async_copy16(src + rstride, dst + 8192);   // rows [128,256)
}

__global__ __launch_bounds__(512, 2) void gemm_8p(
    const unsigned short* __restrict__ Xb,  // bf16 [M][K]
    const unsigned short* __restrict__ Wb,  // bf16 [N][K]
    const float* __restrict__ bias,
    float* __restrict__ C, int M, int N, int K) {
  __shared__ __align__(16) unsigned char smem[131072];
  const int tid = threadIdx.x;
  const int lane = tid & 63, w = tid >> 6;
  const int wm = w >> 2, wn = w & 3;   // 2M x 4N waves, wave tile 128x64
  const int l15 = lane & 15;

  // T1: XCD-aware bijective swizzle (grid % 8 == 0 guaranteed by host gate)
  const int nbn = N >> 8;
  int bid = blockIdx.x;
  {
    const int nwg = gridDim.x;
    if ((nwg & 7) == 0) bid = (bid & 7) * (nwg >> 3) + (bid >> 3);
  }
  const int m0 = (bid / nbn) << 8;
  const int n0 = (bid % nbn) << 8;

  // LDS read offsets (within a 16 KiB unit): row*64 + swizzled 16B chunk
  const int chnk = (((lane >> 4) ^ ((l15 >> 1) & 3)) << 4);
  const int aoff = (wm * 128 + l15) * 64 + chnk;
  const int boff = (wn * 64 + l15) * 64 + chnk;

  // staging: thread -> (row = tid>>2 [+128 for 2nd load], logical chunk lc)
  const int rl = tid >> 2;
  const int lc = (tid & 3) ^ ((tid >> 3) & 3);  // inverse swizzle on source
  const unsigned short* pA = Xb + (size_t)(m0 + rl) * K + lc * 8;
  const unsigned short* pB = Wb + (size_t)(n0 + rl) * K + lc * 8;
  const int rstride = K << 7;   // 128 rows in elements
  const int wuo = w << 10;      // wave-uniform LDS dest offset (lane*16 by HW)

  f32x4 acc[8][4];
#pragma unroll
  for (int i = 0; i < 8; i++)
#pragma unroll
    for (int j = 0; j < 4; j++) acc[i][j] = (f32x4)(0.f);

  const int NT = K >> 6;

  // prologue: stage kh0(0), kh1(0), kh0(1); retire kh0(0); leave 8 in flight
  stage2(pA, rstride, smem + wuo);                         // A-kh0(0)
  stage2(pB, rstride, smem + 65536 + wuo);                 // B-kh0(0)
  stage2(pA + 32, rstride, smem + 16384 + wuo);            // A-kh1(0)
  stage2(pB + 32, rstride, smem + 65536 + 16384 + wuo);    // B-kh1(0)
  stage2(pA + 64, rstride, smem + 32768 + wuo);            // A-kh0(1) -> buf1
  stage2(pB + 64, rstride, smem + 65536 + 32768 + wuo);    // B-kh0(1)
  WAIT_VMCNT(8);   // retire kh0(0); {kh1(0), kh0(1)} stay in flight
  wg_barrier();

  short8 av0, av1, av2, av3, bv0, bv1, bv2, bv3;

  // invariant entering tile t: outstanding = {kh1(t), kh0(t+1)} = 8 loads
  for (int t = 0; t < NT - 2; ++t) {
    const int p = t & 1;
    const unsigned char* Ab = smem + p * 32768;
    const unsigned char* Bb = smem + 65536 + p * 32768;
    unsigned char* Aq1 = smem + (p ^ 1) * 32768 + wuo;          // tile t+1 buf
    unsigned char* Bq1 = smem + 65536 + (p ^ 1) * 32768 + wuo;
    unsigned char* Aq2 = smem + p * 32768 + wuo;                // tile t+2 buf
    unsigned char* Bq2 = smem + 65536 + p * 32768 + wuo;
    const unsigned short* sA1 = pA + (size_t)(t + 1) * 64;
    const unsigned short* sB1 = pB + (size_t)(t + 1) * 64;

    // phase 1: (mh0, kh0) | stage A-kh1(t+1)
    LDA(Ab, 0); LDB(Bb);
    stage2(sA1 + 32, rstride, Aq1 + 16384);
    wg_barrier();
    PRIO1; MM16(0); PRIO0;
    wg_barrier();
    // phase 2: (mh1, kh0), B reused | stage B-kh1(t+1); W2
    LDA(Ab, 1);
    stage2(sB1 + 32, rstride, Bq1 + 16384);
    wg_barrier();
    PRIO1; MM16(4); PRIO0;
    WAIT_VMCNT(8);   // retire kh1(t) (issued ~5 phases ago)
    wg_barrier();
    // phase 3: (mh0, kh1) | stage A-kh0(t+2) (same buf as t; kh0 reads done)
    LDA(Ab + 16384, 0); LDB(Bb + 16384);
    stage2(sA1 + 64, rstride, Aq2);
    wg_barrier();
    PRIO1; MM16(0); PRIO0;
    wg_barrier();
    // phase 4: (mh1, kh1), B reused | stage B-kh0(t+2); W4
    LDA(Ab + 16384, 1);
    stage2(sB1 + 64, rstride, Bq2);
    wg_barrier();
    PRIO1; MM16(4); PRIO0;
    WAIT_VMCNT(8);   // retire kh0(t+1) (issued ~5 phases ago)
    wg_barrier();
  }

  // tile NT-2: stage only kh1(NT-1); waits 8 then 4
  {
    const int p = (NT - 2) & 1;
    const unsigned char* Ab = smem + p * 32768;
    const unsigned char* Bb = smem + 65536 + p * 32768;
    unsigned char* Aq1 = smem + (p ^ 1) * 32768 + wuo;
    unsigned char* Bq1 = smem + 65536 + (p ^ 1) * 32768 + wuo;
    const unsigned short* sA1 = pA + (size_t)(NT - 1) * 64;
    const unsigned short* sB1 = pB + (size_t)(NT - 1) * 64;

    LDA(Ab, 0); LDB(Bb);
    stage2(sA1 + 32, rstride, Aq1 + 16384);    // A-kh1(NT-1)
    wg_barrier();
    PRIO1; MM16(0); PRIO0;
    wg_barrier();
    LDA(Ab, 1);
    stage2(sB1 + 32, rstride, Bq1 + 16384);    // B-kh1(NT-1)
    wg_barrier();
    PRIO1; MM16(4); PRIO0;
    WAIT_VMCNT(8);   // retire kh1(NT-2)
    wg_barrier();
    LDA(Ab + 16384, 0); LDB(Bb + 16384);
    wg_barrier();
    PRIO1; MM16(0); PRIO0;
    wg_barrier();
    LDA(Ab + 16384, 1);
    wg_barrier();
    PRIO1; MM16(4); PRIO0;
    WAIT_VMCNT(4);   // retire kh0(NT-1); kh1(NT-1) stays in flight
    wg_barrier();
  }

  // tile NT-1: no staging
  {
    const int p = (NT - 1) & 1;
    const unsigned char* Ab = smem + p * 32768;
    const unsigned char* Bb = smem + 65536 + p * 32768;
    LDA(Ab, 0); LDB(Bb);
    wg_barrier();
    PRIO1; MM16(0); PRIO0;
    wg_barrier();
    LDA(Ab, 1);
    wg_barrier();
    PRIO1; MM16(4); PRIO0;
    WAIT_VMCNT(0);   // drain kh1(NT-1) (only full drain in the kernel)
    wg_barrier();
    LDA(Ab + 16384, 0); LDB(Bb + 16384);
    wg_barrier();
    PRIO1; MM16(0); PRIO0;
    wg_barrier();
    LDA(Ab + 16384, 1);
    wg_barrier();
    PRIO1; MM16(4); PRIO0;
  }

  // epilogue: 16x16x32 C layout: col = lane&15, row = (lane>>4)*4 + reg
  const int gm = m0 + wm * 128 + ((lane >> 4) << 2);
  const int gn = n0 + wn * 64 + l15;
  float bvs[4];
#pragma unroll
  for (int g = 0; g < 4; ++g) bvs[g] = bias[gn + g * 16];
#pragma unroll
  for (int mf = 0; mf < 8; ++mf) {
    const size_t rb = (size_t)(gm + mf * 16) * N + gn;
#pragma unroll
    for (int r = 0; r < 4; ++r) {
#pragma unroll
      for (int g = 0; g < 4; ++g)
        C[rb + (size_t)r * N + g * 16] = acc[mf][g][r] + bvs[g];
    }
  }
}

// ---- fallback: fused dequant GEMM (odd shapes / tiny ws; never bounded) --
#define BM 128
#define BN 128
#define BK 64

__global__ __launch_bounds__(256) void gemm_fused(
    const float* __restrict__ Xf, const int* __restrict__ Wq,
    const float* __restrict__ Ws, const float* __restrict__ bias,
    float* __restrict__ C, int M, int N, int K) {
  __shared__ unsigned char smem[(BM * BK + BN * BK) * 2];
  const int tid = threadIdx.x;
  const int lane = tid & 63, wid = tid >> 6;
  const int m0 = blockIdx.y * BM, n0 = blockIdx.x * BN;
  const int sr = lane >> 3, fc = (lane & 7) ^ sr;
  const int arow = m0 + wid * 32 + sr, brow = n0 + wid * 32 + sr;
  unsigned char* As = smem;
  unsigned char* Bs = smem + BM * BK * 2;
  unsigned char* stA = As + wid * 4096 + lane * 16;
  unsigned char* stB = Bs + wid * 4096 + lane * 16;
  const int l31 = lane & 31, lh = lane >> 5, le = lane & 7;
  const int wm = (wid & 1) * 64, wn = (wid >> 1) * 64;
  const unsigned char* Aw = As + (wm + l31) * 128;
  const unsigned char* Bw = Bs + (wn + l31) * 128;
  const int Kg = K >> 6;

  f32x16 acc[2][2];
#pragma unroll
  for (int i = 0; i < 2; i++)
#pragma unroll
    for (int j = 0; j < 2; j++) acc[i][j] = (f32x16)(0.f);

  for (int k0 = 0; k0 < K; k0 += BK) {
#pragma unroll
    for (int t = 0; t < 4; t++) {
      const float4v* xa = (const float4v*)(Xf + (size_t)(arow + t * 8) * K + k0 + fc * 8);
      float4v x0 = xa[0], x1 = xa[1];
      ushort8 ra;
      ra[0] = f2bf(x0[0]); ra[1] = f2bf(x0[1]); ra[2] = f2bf(x0[2]); ra[3] = f2bf(x0[3]);
      ra[4] = f2bf(x1[0]); ra[5] = f2bf(x1[1]); ra[6] = f2bf(x1[2]); ra[7] = f2bf(x1[3]);
      *(ushort8*)(stA + t * 1024) = ra;
      const int4v* wq = (const int4v*)(Wq + (size_t)(brow + t * 8) * K + k0 + fc * 8);
      int4v q0 = wq[0], q1 = wq[1];
      float sc = Ws[(size_t)(brow + t * 8) * Kg + (k0 >> 6)];
      ushort8 rb;
      rb[0] = f2bf((float)q0[0] * sc); rb[1] = f2bf((float)q0[1] * sc);
      rb[2] = f2bf((float)q0[2] * sc); rb[3] = f2bf((float)q0[3] * sc);
      rb[4] = f2bf((float)q1[0] * sc); rb[5] = f2bf((float)q1[1] * sc);
      rb[6] = f2bf((float)q1[2] * sc); rb[7] = f2bf((float)q1[3] * sc);
      *(ushort8*)(stB + t * 1024) = rb;
    }
    __syncthreads();
#pragma unroll
    for (int s = 0; s < 4; s++) {
      const int off = ((s + 4 * lh) ^ le) << 4;
      short8 a0 = *(const short8*)(Aw + off);
      short8 a1 = *(const short8*)(Aw + 4096 + off);
      short8 b0 = *(const short8*)(Bw + off);
      short8 b1 = *(const short8*)(Bw + 4096 + off);
      acc[0][0] = __builtin_amdgcn_mfma_f32_32x32x16_bf16(a0, b0, acc[0][0], 0, 0, 0);
      acc[0][1] = __builtin_amdgcn_mfma_f32_32x32x16_bf16(a0, b1, acc[0][1], 0, 0, 0);
      acc[1][0] = __builtin_amdgcn_mfma_f32_32x32x16_bf16(a1, b0, acc[1][0], 0, 0, 0);
      acc[1][1] = __builtin_amdgcn_mfma_f32_32x32x16_bf16(a1, b1, acc[1][1], 0, 0, 0);
    }
    __syncthreads();
  }

  const int gm = m0 + wm + 4 * lh, gn = n0 + wn + l31;
#pragma unroll
  for (int j = 0; j < 2; j++) {
    const int col = gn + j * 32;
    const float bv = bias[col];
#pragma unroll
    for (int i = 0; i < 2; i++) {
      const int rbase = gm + i * 32;
      f32x16 v = acc[i][j];
#pragma unroll
      for (int r = 0; r < 16; r++) {
        const int row = rbase + (r & 3) + 8 * (r >> 2);
        C[(size_t)row * N + col] = v[r] + bv;
      }
    }
  }
}

extern "C" void kernel_launch(void* const* d_in, const int* in_sizes, int n_in,
                              void* d_out, int out_size, void* d_ws, size_t ws_size,
                              hipStream_t stream) {
  const float* x = (const float*)d_in[0];
  const int* wq = (const int*)d_in[1];
  const float* wsc = (const float*)d_in[2];
  const float* bias = (const float*)d_in[3];
  float* out = (float*)d_out;

  const int N = in_sizes[3];            // D_out (bias length)
  const int K = in_sizes[1] / N;        // D_in
  const int M = in_sizes[0] / K;        // B*S

  const size_t needX = (size_t)M * K * 2;
  const size_t needW = (size_t)N * K * 2;
  const bool big = (M % 256 == 0) && (N % 256 == 0) && (K % 64 == 0) && (K >= 128);

  if (big && ws_size >= needX + needW) {
    unsigned short* Xb = (unsigned short*)d_ws;
    unsigned short* Wb = (unsigned short*)((char*)d_ws + needX);
    const int n8x = (M * K) / 8, n8w = (N * K) / 8;
    // grid-stride cvt: ~8 blocks/CU, X:W work ratio = 2:1
    const int gx = 1376, gw = 688;
    cvt_kernel<<<gx + gw, 256, 0, stream>>>(x, wq, wsc, Xb, Wb, n8x, n8w, gx);
    dim3 grid((M / 256) * (N / 256));
    gemm_8p<<<grid, 512, 0, stream>>>(Xb, Wb, bias, out, M, N, K);
  } else {
    dim3 grid(N / BN, M / BM), block(256);
    gemm_fused<<<grid, block, 0, stream>>>(x, wq, wsc, bias, out, M, N, K);
  }
}